// Round 2
// baseline (1289.117 us; speedup 1.0000x reference)
//
#include <hip/hip_runtime.h>
#include <hip/hip_bf16.h>

typedef __attribute__((ext_vector_type(8))) short bf16x8;
typedef __attribute__((ext_vector_type(4))) float f32x4;

#define MFMA16(a, b, c) __builtin_amdgcn_mfma_f32_16x16x32_bf16(a, b, c, 0, 0, 0)

__device__ inline short f2bf(float f) {
    union { __hip_bfloat16 h; short s; } u;
    u.h = __float2bfloat16(f);
    return u.s;
}

__device__ inline bf16x8 cvt8(const float* __restrict__ p) {
    f32x4 a = *reinterpret_cast<const f32x4*>(p);
    f32x4 b = *reinterpret_cast<const f32x4*>(p + 4);
    bf16x8 r;
    r[0] = f2bf(a[0]); r[1] = f2bf(a[1]); r[2] = f2bf(a[2]); r[3] = f2bf(a[3]);
    r[4] = f2bf(b[0]); r[5] = f2bf(b[1]); r[6] = f2bf(b[2]); r[7] = f2bf(b[3]);
    return r;
}

// ---------------------------------------------------------------------------
// Kernel 1: QKV projection. y = x @ W^T + b  (W is [out,in], K-contiguous).
// grid.x = M/64 row tiles (M = B*S = 32768), grid.y = 3 (q,k,v).
// 4 waves/block, each wave computes 16 rows x 256 cols via 16x16x32 bf16 MFMA.
// q,k written [S][D] bf16; v written transposed [D][S] bf16 (LDS bounce).
// ---------------------------------------------------------------------------
__global__ __launch_bounds__(256, 2) void qkv_kernel(
    const float* __restrict__ x,
    const float* __restrict__ Wq, const float* __restrict__ bq,
    const float* __restrict__ Wk, const float* __restrict__ bk,
    const float* __restrict__ Wv, const float* __restrict__ bv,
    __hip_bfloat16* __restrict__ qo, __hip_bfloat16* __restrict__ ko,
    __hip_bfloat16* __restrict__ vto)
{
    const int proj = blockIdx.y;
    const float* __restrict__ W    = proj == 0 ? Wq : (proj == 1 ? Wk : Wv);
    const float* __restrict__ bias = proj == 0 ? bq : (proj == 1 ? bk : bv);
    const int wave = threadIdx.x >> 6;
    const int lane = threadIdx.x & 63;
    const int l15 = lane & 15, l4 = lane >> 4;
    const int row0  = blockIdx.x * 64;       // block's global row base
    const int wrow0 = row0 + wave * 16;      // wave's row base

    // A fragments: 16 rows of x, all 256 K, converted to bf16 inline.
    bf16x8 af[8];
    const float* __restrict__ xr = x + (size_t)(wrow0 + l15) * 256 + l4 * 8;
#pragma unroll
    for (int kc = 0; kc < 8; ++kc) af[kc] = cvt8(xr + kc * 32);

    f32x4 acc[16];
#pragma unroll
    for (int nf = 0; nf < 16; ++nf) {
        f32x4 z = {0.f, 0.f, 0.f, 0.f};
        acc[nf] = z;
    }

#pragma unroll
    for (int nf = 0; nf < 16; ++nf) {
        const float* __restrict__ wr = W + (size_t)(nf * 16 + l15) * 256 + l4 * 8;
#pragma unroll
        for (int kc = 0; kc < 8; ++kc) {
            bf16x8 bfrag = cvt8(wr + kc * 32);
            acc[nf] = MFMA16(af[kc], bfrag, acc[nf]);
        }
    }

    // Stage block's 64x256 output tile in LDS (bf16), bias added.
    __shared__ short tile[64][264];   // pad 264 to break bank alignment
#pragma unroll
    for (int nf = 0; nf < 16; ++nf) {
        int col = nf * 16 + l15;
        float bv_ = bias[col];
#pragma unroll
        for (int r = 0; r < 4; ++r)
            tile[wave * 16 + l4 * 4 + r][col] = f2bf(acc[nf][r] + bv_);
    }
    __syncthreads();

    if (proj < 2) {
        // linear coalesced copy-out: 64 rows x 256 cols = 2048 chunks of 8 elems
        __hip_bfloat16* __restrict__ dst = (proj == 0 ? qo : ko) + (size_t)row0 * 256;
#pragma unroll
        for (int i = 0; i < 8; ++i) {
            int chunk = threadIdx.x + i * 256;
            int r = chunk >> 5, cc = chunk & 31;
            bf16x8 v = *reinterpret_cast<const bf16x8*>(&tile[r][cc * 8]);
            *reinterpret_cast<bf16x8*>(dst + chunk * 8) = v;
        }
    } else {
        // transpose copy-out: thread t owns output feature d = t
        int d  = threadIdx.x;
        int bb = row0 >> 12;        // batch
        int s0 = row0 & 4095;       // seq offset within batch
        __hip_bfloat16* __restrict__ dst = vto + ((size_t)bb * 256 + d) * 4096 + s0;
#pragma unroll
        for (int i = 0; i < 8; ++i) {
            bf16x8 v;
#pragma unroll
            for (int j = 0; j < 8; ++j) v[j] = tile[i * 8 + j][d];
            *reinterpret_cast<bf16x8*>(dst + i * 8) = v;
        }
    }
}

// ---------------------------------------------------------------------------
// Kernel 2: flash attention + residual.
// grid = (S/64, B); 4 waves/block, each wave owns 16 q-rows, KV blocks of 64.
// Q held in registers; K read [S][D], V read transposed [D][S] (both bf16,
// contiguous 16B fragment loads, L2-resident per batch). Online softmax is
// wave-parallel via shfl_xor over the 16-lane column groups. P goes through
// a small per-wave LDS buffer to re-layout C-frags -> A-frags.
// ---------------------------------------------------------------------------
__global__ __launch_bounds__(256, 2) void attn_kernel(
    const __hip_bfloat16* __restrict__ q,
    const __hip_bfloat16* __restrict__ k,
    const __hip_bfloat16* __restrict__ vt,
    const float* __restrict__ x,
    float* __restrict__ out)
{
    const int b = blockIdx.y;
    const int wave = threadIdx.x >> 6, lane = threadIdx.x & 63;
    const int l15 = lane & 15, l4 = lane >> 4;
    const int qrow0 = blockIdx.x * 64 + wave * 16;   // within batch

    const __hip_bfloat16* __restrict__ qb = q  + (size_t)b * 4096 * 256;
    const __hip_bfloat16* __restrict__ kb = k  + (size_t)b * 4096 * 256;
    const __hip_bfloat16* __restrict__ vb = vt + (size_t)b * 256 * 4096;

    // Q A-fragments: row = l15, d = kc*32 + l4*8 + j
    bf16x8 qf[8];
    const __hip_bfloat16* __restrict__ qr = qb + (size_t)(qrow0 + l15) * 256 + l4 * 8;
#pragma unroll
    for (int kc = 0; kc < 8; ++kc)
        qf[kc] = *reinterpret_cast<const bf16x8*>(qr + kc * 32);

    f32x4 o[16];
#pragma unroll
    for (int df = 0; df < 16; ++df) {
        f32x4 z = {0.f, 0.f, 0.f, 0.f};
        o[df] = z;
    }
    float m[4]    = {-INFINITY, -INFINITY, -INFINITY, -INFINITY};
    float lsum[4] = {0.f, 0.f, 0.f, 0.f};

    __shared__ short plds[4][16][72];   // per-wave P buffer, row pitch 144B (16B-mult)
    short (*pw)[72] = plds[wave];

    const float scale = 0.0625f;   // 1/sqrt(256)

    for (int kv = 0; kv < 4096; kv += 64) {
        // ---- QK^T: s[nf] = Q(16x256) . K^T(256x16), keys nf*16+l15
        f32x4 s[4];
#pragma unroll
        for (int nf = 0; nf < 4; ++nf) {
            f32x4 z = {0.f, 0.f, 0.f, 0.f};
            s[nf] = z;
        }
#pragma unroll
        for (int nf = 0; nf < 4; ++nf) {
            const __hip_bfloat16* __restrict__ kr =
                kb + (size_t)(kv + nf * 16 + l15) * 256 + l4 * 8;
#pragma unroll
            for (int kc = 0; kc < 8; ++kc) {
                bf16x8 kf = *reinterpret_cast<const bf16x8*>(kr + kc * 32);
                s[nf] = MFMA16(qf[kc], kf, s[nf]);
            }
        }

        // ---- online softmax (rows owned by 16-lane groups)
        float p[4][4];
#pragma unroll
        for (int r = 0; r < 4; ++r) {
            float mx = fmaxf(fmaxf(s[0][r], s[1][r]), fmaxf(s[2][r], s[3][r])) * scale;
#pragma unroll
            for (int d = 1; d < 16; d <<= 1) mx = fmaxf(mx, __shfl_xor(mx, d));
            float mnew  = fmaxf(m[r], mx);
            float alpha = __expf(m[r] - mnew);
            m[r] = mnew;
            float rs = 0.f;
#pragma unroll
            for (int nf = 0; nf < 4; ++nf) {
                float pv_ = __expf(s[nf][r] * scale - mnew);
                p[nf][r] = pv_;
                rs += pv_;
            }
#pragma unroll
            for (int d = 1; d < 16; d <<= 1) rs += __shfl_xor(rs, d);
            lsum[r] = lsum[r] * alpha + rs;
#pragma unroll
            for (int df = 0; df < 16; ++df) o[df][r] *= alpha;
        }

        // ---- P: C-layout -> LDS -> A-layout (wave-internal, DS in-order)
#pragma unroll
        for (int nf = 0; nf < 4; ++nf)
#pragma unroll
            for (int r = 0; r < 4; ++r)
                pw[l4 * 4 + r][nf * 16 + l15] = f2bf(p[nf][r]);

        bf16x8 pf[2];
#pragma unroll
        for (int kc2 = 0; kc2 < 2; ++kc2)
            pf[kc2] = *reinterpret_cast<const bf16x8*>(&pw[l15][kc2 * 32 + l4 * 8]);

        // ---- PV: o[df] += P(16x64) . V(64x16), V from [D][S] layout
#pragma unroll
        for (int df = 0; df < 16; ++df) {
            const __hip_bfloat16* __restrict__ vr =
                vb + (size_t)(df * 16 + l15) * 4096 + kv + l4 * 8;
#pragma unroll
            for (int kc2 = 0; kc2 < 2; ++kc2) {
                bf16x8 vf = *reinterpret_cast<const bf16x8*>(vr + kc2 * 32);
                o[df] = MFMA16(pf[kc2], vf, o[df]);
            }
        }
    }

    // ---- epilogue: normalize, add residual, store fp32
#pragma unroll
    for (int r = 0; r < 4; ++r) {
        float inv = 1.0f / lsum[r];
        size_t row = (size_t)b * 4096 + qrow0 + l4 * 4 + r;
#pragma unroll
        for (int df = 0; df < 16; ++df) {
            int col = df * 16 + l15;
            out[row * 256 + col] = o[df][r] * inv + x[row * 256 + col];
        }
    }
}

// ---------------------------------------------------------------------------
extern "C" void kernel_launch(void* const* d_in, const int* in_sizes, int n_in,
                              void* d_out, int out_size, void* d_ws, size_t ws_size,
                              hipStream_t stream) {
    const float* x  = (const float*)d_in[0];
    const float* Wq = (const float*)d_in[1];
    const float* bq = (const float*)d_in[2];
    const float* Wk = (const float*)d_in[3];
    const float* bk = (const float*)d_in[4];
    const float* Wv = (const float*)d_in[5];
    const float* bv = (const float*)d_in[6];
    float* out = (float*)d_out;

    char* ws = (char*)d_ws;
    __hip_bfloat16* qb  = (__hip_bfloat16*)ws;                              // 16 MB
    __hip_bfloat16* kb  = (__hip_bfloat16*)(ws + (size_t)16 * 1024 * 1024); // 16 MB
    __hip_bfloat16* vtb = (__hip_bfloat16*)(ws + (size_t)32 * 1024 * 1024); // 16 MB

    dim3 gA(512, 3), bA(256, 1, 1);
    qkv_kernel<<<gA, bA, 0, stream>>>(x, Wq, bq, Wk, bk, Wv, bv, qb, kb, vtb);

    dim3 gB(64, 8), bB(256, 1, 1);
    attn_kernel<<<gB, bB, 0, stream>>>(qb, kb, vtb, x, out);
}

// Round 3
// 353.371 us; speedup vs baseline: 3.6481x; 3.6481x over previous
//
#include <hip/hip_runtime.h>
#include <hip/hip_bf16.h>

typedef __attribute__((ext_vector_type(8))) short bf16x8;
typedef __attribute__((ext_vector_type(4))) float f32x4;

#define MFMA16(a, b, c) __builtin_amdgcn_mfma_f32_16x16x32_bf16(a, b, c, 0, 0, 0)

__device__ __forceinline__ short f2bf(float f) {
    union { __hip_bfloat16 h; short s; } u;
    u.h = __float2bfloat16(f);
    return u.s;
}

__device__ __forceinline__ bf16x8 cvt8(const float* __restrict__ p) {
    f32x4 a = *reinterpret_cast<const f32x4*>(p);
    f32x4 b = *reinterpret_cast<const f32x4*>(p + 4);
    bf16x8 r;
    r[0] = f2bf(a[0]); r[1] = f2bf(a[1]); r[2] = f2bf(a[2]); r[3] = f2bf(a[3]);
    r[4] = f2bf(b[0]); r[5] = f2bf(b[1]); r[6] = f2bf(b[2]); r[7] = f2bf(b[3]);
    return r;
}

typedef __attribute__((address_space(1))) const unsigned int g_u32;
typedef __attribute__((address_space(3))) unsigned int l_u32;
__device__ __forceinline__ void gld16(const void* g, void* l) {
    __builtin_amdgcn_global_load_lds((g_u32*)(g), (l_u32*)(l), 16, 0, 0);
}

// ---------------------------------------------------------------------------
// Kernel 0: convert Wq|Wk|Wv (fp32, 3x65536) to bf16, stored in d_out scratch.
// ---------------------------------------------------------------------------
__global__ void wcvt_kernel(const float* __restrict__ Wq, const float* __restrict__ Wk,
                            const float* __restrict__ Wv, short* __restrict__ Wb)
{
    int t = blockIdx.x * 256 + threadIdx.x;      // 0..24575
    int idx = t * 8;                              // elem index, 0..196600
    const float* src = idx < 65536 ? Wq + idx
                     : (idx < 131072 ? Wk + (idx - 65536) : Wv + (idx - 131072));
    *reinterpret_cast<bf16x8*>(Wb + idx) = cvt8(src);
}

// ---------------------------------------------------------------------------
// Kernel 1: fused QKV projection. Each block: 64 rows x 256 cols, all 3 projs.
// x loaded+converted to bf16 ONCE, reused for q,k,v. W read as bf16.
// q,k written [S][D] bf16; v written transposed [D][S] bf16 (LDS bounce).
// ---------------------------------------------------------------------------
__global__ __launch_bounds__(256, 2) void qkv_kernel(
    const float* __restrict__ x, const short* __restrict__ Wb,
    const float* __restrict__ bq, const float* __restrict__ bk, const float* __restrict__ bv,
    short* __restrict__ qo, short* __restrict__ ko, short* __restrict__ vto)
{
    const int wave = threadIdx.x >> 6;
    const int lane = threadIdx.x & 63;
    const int l15 = lane & 15, l4 = lane >> 4;
    const int row0  = blockIdx.x * 64;
    const int wrow0 = row0 + wave * 16;

    bf16x8 af[8];
    const float* __restrict__ xr = x + (size_t)(wrow0 + l15) * 256 + l4 * 8;
#pragma unroll
    for (int kc = 0; kc < 8; ++kc) af[kc] = cvt8(xr + kc * 32);

    __shared__ short tile[64][264];

    for (int proj = 0; proj < 3; ++proj) {
        const short* __restrict__ W = Wb + proj * 65536;
        const float* __restrict__ bias = proj == 0 ? bq : (proj == 1 ? bk : bv);

        f32x4 acc[16];
#pragma unroll
        for (int nf = 0; nf < 16; ++nf) { f32x4 z = {0.f,0.f,0.f,0.f}; acc[nf] = z; }

#pragma unroll
        for (int nf = 0; nf < 16; ++nf) {
            const short* __restrict__ wr = W + (nf * 16 + l15) * 256 + l4 * 8;
#pragma unroll
            for (int kc = 0; kc < 8; ++kc) {
                bf16x8 bfrag = *reinterpret_cast<const bf16x8*>(wr + kc * 32);
                acc[nf] = MFMA16(af[kc], bfrag, acc[nf]);
            }
        }

        if (proj) __syncthreads();   // previous copy-out finished before reuse
#pragma unroll
        for (int nf = 0; nf < 16; ++nf) {
            int col = nf * 16 + l15;
            float bv_ = bias[col];
#pragma unroll
            for (int r = 0; r < 4; ++r)
                tile[wave * 16 + l4 * 4 + r][col] = f2bf(acc[nf][r] + bv_);
        }
        __syncthreads();

        if (proj < 2) {
            short* __restrict__ dst = (proj == 0 ? qo : ko) + (size_t)row0 * 256;
#pragma unroll
            for (int i = 0; i < 8; ++i) {
                int chunk = threadIdx.x + i * 256;
                int r = chunk >> 5, cc = chunk & 31;
                bf16x8 v = *reinterpret_cast<const bf16x8*>(&tile[r][cc * 8]);
                *reinterpret_cast<bf16x8*>(dst + chunk * 8) = v;
            }
        } else {
            int d  = threadIdx.x;
            int bb = row0 >> 12;
            int s0 = row0 & 4095;
            short* __restrict__ dst = vto + ((size_t)bb * 256 + d) * 4096 + s0;
#pragma unroll
            for (int i = 0; i < 8; ++i) {
                bf16x8 v;
#pragma unroll
                for (int j = 0; j < 8; ++j) v[j] = tile[i * 8 + j][d];
                *reinterpret_cast<bf16x8*>(dst + i * 8) = v;
            }
        }
    }
}

// ---------------------------------------------------------------------------
// Kernel 2: flash attention + residual. 8 waves, 128 q-rows/block, KVBLK=64.
// K double-buffered in LDS (global_load_lds w16, read-pattern layout ->
// conflict-free b128 reads). V staged global->reg early, ds_write late (T14).
// Defer-max (T13). Grid 256 1-D: batch = id&7 (XCD-affine), qtile = id>>3.
// LDS: K 2x32KB + V 32KB + P 18KB = 114 KB.
// ---------------------------------------------------------------------------
__global__ __launch_bounds__(512, 2) void attn_kernel(
    const short* __restrict__ q, const short* __restrict__ k,
    const short* __restrict__ vt, const float* __restrict__ x,
    float* __restrict__ out)
{
    const int id = blockIdx.x;
    const int b = id & 7, qt = id >> 3;
    const int tid = threadIdx.x;
    const int wave = tid >> 6, lane = tid & 63;
    const int l15 = lane & 15, l4 = lane >> 4;
    const int qrow0 = qt * 128 + wave * 16;

    const short* __restrict__ qb = q  + (size_t)b * 4096 * 256;
    const short* __restrict__ kb = k  + (size_t)b * 4096 * 256;
    const short* __restrict__ vb = vt + (size_t)b * 256 * 4096;

    __shared__ short klds[2][16384];   // slot c=(nf*512+kc*64+l15*4+l4), 16B each
    __shared__ short vlds[16384];      // slot c=(df*128+kc2*64+l15*4+l4)
    __shared__ short plds[8][16][72];

    // Q fragments: lane(l4,l15) holds Q[qrow0+l15][kc*32+l4*8 ..+7]
    bf16x8 qf[8];
    const short* __restrict__ qr = qb + (size_t)(qrow0 + l15) * 256 + l4 * 8;
#pragma unroll
    for (int kc = 0; kc < 8; ++kc)
        qf[kc] = *reinterpret_cast<const bf16x8*>(qr + kc * 32);

    f32x4 o[16];
#pragma unroll
    for (int df = 0; df < 16; ++df) { f32x4 z = {0.f,0.f,0.f,0.f}; o[df] = z; }
    float m2[4]   = {-INFINITY, -INFINITY, -INFINITY, -INFINITY};
    float lsum[4] = {0.f, 0.f, 0.f, 0.f};

    const float cs = 0.0625f * 1.44269504f;   // scale * log2(e)

    bf16x8 vreg[4];

    // ---- staging helpers (c = i*512 + tid) ----
#define STAGE_K(KV, BUF)                                                      \
    {                                                                         \
        _Pragma("unroll")                                                     \
        for (int i = 0; i < 4; ++i) {                                         \
            int c = i * 512 + tid;                                            \
            int nf = c >> 9, kc = (c >> 6) & 7, rr = (c >> 2) & 15, c4 = c & 3;\
            gld16(kb + (size_t)((KV) + nf * 16 + rr) * 256 + (kc * 4 + c4) * 8,\
                  &klds[BUF][c * 8]);                                         \
        }                                                                     \
    }
#define LOAD_V(KV)                                                            \
    {                                                                         \
        _Pragma("unroll")                                                     \
        for (int i = 0; i < 4; ++i) {                                         \
            int c = i * 512 + tid;                                            \
            int df = c >> 7, k2 = (c >> 6) & 1, rr = (c >> 2) & 15, c4 = c & 3;\
            vreg[i] = *reinterpret_cast<const bf16x8*>(                       \
                vb + (size_t)(df * 16 + rr) * 4096 + (KV) + (k2 * 4 + c4) * 8);\
        }                                                                     \
    }
#define WRITE_V()                                                             \
    {                                                                         \
        _Pragma("unroll")                                                     \
        for (int i = 0; i < 4; ++i) {                                         \
            int c = i * 512 + tid;                                            \
            *reinterpret_cast<bf16x8*>(&vlds[c * 8]) = vreg[i];               \
        }                                                                     \
    }

    // prologue: stage tile 0
    STAGE_K(0, 0);
    LOAD_V(0);
    __syncthreads();          // drains vmcnt -> K in LDS, vreg ready
    WRITE_V();
    __syncthreads();

    short (*pw)[72] = plds[wave];

    for (int t = 0; t < 64; ++t) {
        const int kv = t * 64;
        const int cur = t & 1;
        if (t < 63) { STAGE_K(kv + 64, cur ^ 1); LOAD_V(kv + 64); }

        // ---- QK^T from LDS (conflict-free: 64 consecutive slots per read)
        f32x4 s[4];
#pragma unroll
        for (int nf = 0; nf < 4; ++nf) { f32x4 z = {0.f,0.f,0.f,0.f}; s[nf] = z; }
        const short* __restrict__ kbase = klds[cur];
#pragma unroll
        for (int nf = 0; nf < 4; ++nf)
#pragma unroll
            for (int kc = 0; kc < 8; ++kc) {
                bf16x8 kf = *reinterpret_cast<const bf16x8*>(
                    kbase + (nf * 512 + kc * 64 + l15 * 4 + l4) * 8);
                s[nf] = MFMA16(qf[kc], kf, s[nf]);
            }

        // ---- online softmax (log2 domain), defer-max rescale
        float tt[4][4];
#pragma unroll
        for (int nf = 0; nf < 4; ++nf)
#pragma unroll
            for (int r = 0; r < 4; ++r) tt[nf][r] = s[nf][r] * cs;

        float mx[4];
#pragma unroll
        for (int r = 0; r < 4; ++r) {
            float v = fmaxf(fmaxf(tt[0][r], tt[1][r]), fmaxf(tt[2][r], tt[3][r]));
#pragma unroll
            for (int d = 1; d < 16; d <<= 1) v = fmaxf(v, __shfl_xor(v, d));
            mx[r] = v;
        }
        bool grow = (mx[0] > m2[0]) | (mx[1] > m2[1]) | (mx[2] > m2[2]) | (mx[3] > m2[3]);
        if (__any(grow)) {
#pragma unroll
            for (int r = 0; r < 4; ++r) {
                float mn = fmaxf(m2[r], mx[r]);
                float al = exp2f(m2[r] - mn);
                m2[r] = mn;
                lsum[r] *= al;
#pragma unroll
                for (int df = 0; df < 16; ++df) o[df][r] *= al;
            }
        }

        float p[4][4];
#pragma unroll
        for (int r = 0; r < 4; ++r) {
            float rs = 0.f;
#pragma unroll
            for (int nf = 0; nf < 4; ++nf) {
                float pv_ = exp2f(tt[nf][r] - m2[r]);
                p[nf][r] = pv_;
                rs += pv_;
            }
#pragma unroll
            for (int d = 1; d < 16; d <<= 1) rs += __shfl_xor(rs, d);
            lsum[r] += rs;
        }

        // ---- P: C-layout -> per-wave LDS -> A-layout
#pragma unroll
        for (int nf = 0; nf < 4; ++nf)
#pragma unroll
            for (int r = 0; r < 4; ++r)
                pw[l4 * 4 + r][nf * 16 + l15] = f2bf(p[nf][r]);

        bf16x8 pf[2];
#pragma unroll
        for (int kc2 = 0; kc2 < 2; ++kc2)
            pf[kc2] = *reinterpret_cast<const bf16x8*>(&pw[l15][kc2 * 32 + l4 * 8]);

        // ---- PV from LDS (conflict-free layout)
#pragma unroll
        for (int df = 0; df < 16; ++df)
#pragma unroll
            for (int kc2 = 0; kc2 < 2; ++kc2) {
                bf16x8 vf = *reinterpret_cast<const bf16x8*>(
                    vlds + (df * 128 + kc2 * 64 + l15 * 4 + l4) * 8);
                o[df] = MFMA16(pf[kc2], vf, o[df]);
            }

        __syncthreads();           // all PV reads done; prefetch drained
        if (t < 63) WRITE_V();     // V[t+1] into vlds
        __syncthreads();           // vlds coherent for next iteration
    }

    // ---- epilogue: normalize, residual, fp32 store
#pragma unroll
    for (int r = 0; r < 4; ++r) {
        float inv = 1.0f / lsum[r];
        size_t row = (size_t)b * 4096 + qrow0 + l4 * 4 + r;
#pragma unroll
        for (int df = 0; df < 16; ++df) {
            int col = df * 16 + l15;
            out[row * 256 + col] = o[df][r] * inv + x[row * 256 + col];
        }
    }
#undef STAGE_K
#undef LOAD_V
#undef WRITE_V
}

// ---------------------------------------------------------------------------
extern "C" void kernel_launch(void* const* d_in, const int* in_sizes, int n_in,
                              void* d_out, int out_size, void* d_ws, size_t ws_size,
                              hipStream_t stream) {
    const float* x  = (const float*)d_in[0];
    const float* Wq = (const float*)d_in[1];
    const float* bq = (const float*)d_in[2];
    const float* Wk = (const float*)d_in[3];
    const float* bk = (const float*)d_in[4];
    const float* Wv = (const float*)d_in[5];
    const float* bv = (const float*)d_in[6];
    float* out = (float*)d_out;

    char* ws = (char*)d_ws;
    short* qb  = (short*)ws;                               // 16 MB bf16 [B*S][D]
    short* kb  = (short*)(ws + (size_t)16 * 1024 * 1024);  // 16 MB bf16 [B*S][D]
    short* vtb = (short*)(ws + (size_t)32 * 1024 * 1024);  // 16 MB bf16 [B][D][S]
    // W bf16 scratch lives in d_out (first 384 KB); attn overwrites out later.
    short* Wb = (short*)d_out;

    wcvt_kernel<<<96, 256, 0, stream>>>(Wq, Wk, Wv, Wb);

    qkv_kernel<<<512, 256, 0, stream>>>(x, Wb, bq, bk, bv, qb, kb, vtb);

    attn_kernel<<<256, 512, 0, stream>>>(qb, kb, vtb, x, out);
}